// Round 14
// baseline (786.805 us; speedup 1.0000x reference)
//
#include <hip/hip_runtime.h>
#include <hip/hip_fp16.h>

// ---------------------------------------------------------------------------
// GNNDecoder, Wenc folded past the aggregation (linearity):
//   px16 = fp16(prelu(x)) ; px16[mask]=0 (mask bitmap folded into px phase)
//   agg16[dst] = px16[dst] + sum_{edges->dst} px16[src]   (direct LDS-accum)
//   hid16 = relu( agg16 @ Wc^T + S + c*T + d*U )  (Wc=W1@Wenc, tabs=emb@W1^T)
//   out = hid16 @ W2^T + b2
// N=50000, E=800000, D=128, DFF=256, OUT=119
//
// GEMMs: v_mfma_f32_16x16x32_f16, fp32 accum, weights LDS-staged (row stride
// 272B/528B == 4 mod 32 dwords -> 2-way bank aliasing, free), 2 blocks/CU.
// Aggregation (R13): one kernel, 391 buckets x 128 dsts; binned records
// stream into a 64KB fp32 LDS accumulator via ds_add_f32 (replaces the
// bucket-sort scatter + register-chain gather: k_agg was queue-limited at
// ~7cyc/line, so the win is removing k_bucket + sorted traffic + 1 launch,
// and fp32 accumulation improves numerics over fp16 chains).
// R6 lesson: binning reserves cursors via per-block LDS aggregation.
// R11 lesson: occupancy beats fusion for the MFMA kernels.
// ---------------------------------------------------------------------------

typedef unsigned long long ull;
typedef _Float16 half8 __attribute__((ext_vector_type(8)));
typedef float    f32x4 __attribute__((ext_vector_type(4)));

#define MFMA16(a, b, c) __builtin_amdgcn_mfma_f32_16x16x32_f16(a, b, c, 0, 0, 0)
#define BCAP 2560   // bucket capacity (mean 2048, sigma ~45 -> +11 sigma)
#define EPB  2048   // edges per binning block (8 per thread)

// ---- K_wconv: Wc = W1@Wenc (fp16), W2 pad-convert, emb@W1^T tables,
// ----          gcur zero, mask bitmap  (194 blocks) ------------------------
__global__ __launch_bounds__(256) void k_wconv(const float* __restrict__ Wen,
                                               const float* __restrict__ W1,
                                               const float* __restrict__ W2,
                                               const float* __restrict__ b1,
                                               const float* __restrict__ emb1,
                                               const float* __restrict__ emb2,
                                               const int* __restrict__ midx,
                                               __half* __restrict__ Wc16,
                                               __half* __restrict__ W2_16p,
                                               float* __restrict__ tabs,
                                               int* __restrict__ gcur,
                                               unsigned int* __restrict__ bm,
                                               int n, int E, int nm)
{
    int b = blockIdx.x, t = threadIdx.x;
    if (b < 128) {                            // Wc rows 2b, 2b+1
        __shared__ float We[128 * 128];
        for (int i = t; i < 4096; i += 256) {
            int j = i >> 5, k4 = (i & 31) << 2;
            *(float4*)(We + (j << 7) + k4) = *(const float4*)(Wen + (j << 7) + k4);
        }
        __syncthreads();
        int r = (b << 1) | (t >> 7);
        int k = t & 127;
        const float* w1r = W1 + ((size_t)r << 7);
        float acc = 0.f;
#pragma unroll 8
        for (int j = 0; j < 128; ++j)
            acc = fmaf(w1r[j], We[(j << 7) + k], acc);
        Wc16[(r << 7) + k] = __float2half(acc);
    } else if (b < 192) {                     // W2 pad-convert (2 elems/thread)
#pragma unroll
        for (int u = 0; u < 2; ++u) {
            int i = (b - 128) * 512 + u * 256 + t;    // 0..32767
            int r = i >> 8;
            W2_16p[i] = (r < 119) ? __float2half(W2[i]) : __half(0.0f);
        }
    } else if (b == 192) {                    // S,T0..2,U0..2 tables
        int col = t;
        const float* w1r = W1 + ((size_t)col << 7);
        float s = 0.f, t0 = 0.f, t1 = 0.f, t2 = 0.f,
              u0 = 0.f, u1 = 0.f, u2 = 0.f;
        for (int j = 0; j < 128; ++j) {
            float w = w1r[j];
            s  = fmaf(emb1[512 + j] + emb2[j], w, s);
            t0 = fmaf(emb1[j],        w, t0);
            t1 = fmaf(emb1[128 + j],  w, t1);
            t2 = fmaf(emb1[256 + j],  w, t2);
            u0 = fmaf(emb2[j],        w, u0);
            u1 = fmaf(emb2[128 + j],  w, u1);
            u2 = fmaf(emb2[256 + j],  w, u2);
        }
        tabs[col]            = s + b1[col];
        tabs[256 + col]      = t0;
        tabs[512 + col]      = t1;
        tabs[768 + col]      = t2;
        tabs[1024 + col]     = u0;
        tabs[1280 + col]     = u1;
        tabs[1536 + col]     = u2;
    } else {                                  // b == 193: gcur, bitmap
        for (int i = t; i < 512; i += 256) gcur[i] = 0;
        int nw = (n + 31) >> 5;
        for (int i = t; i < nw; i += 256) bm[i] = 0u;
        __syncthreads();
        for (int m = t; m < nm; m += 256) {
            int node = midx[m];
            atomicOr(&bm[node >> 5], 1u << (node & 31));
        }
    }
}

// ---- K_pre: {px16 = fp16(prelu(x)), mask via bitmap} + {edge binning} ----
// record: src(16) | et(2)<<16 | ed(2)<<18 | dstlow7<<20 ; bucket = dst>>7
__global__ __launch_bounds__(256) void k_pre(const float* __restrict__ x,
                                             const float* __restrict__ prelu_a,
                                             const unsigned int* __restrict__ bm,
                                             uint2* __restrict__ px16u2,
                                             const int* __restrict__ ei,
                                             const int* __restrict__ ea,
                                             int* __restrict__ gcur,
                                             unsigned int* __restrict__ binned,
                                             int n, int E, int nbPx, int nbBin)
{
    __shared__ int lcnt[512];
    int t = threadIdx.x;

    if ((int)blockIdx.x >= nbPx) {            // ---- binning blocks ----
        int b = blockIdx.x - nbPx;
        int e0 = b * EPB;
        lcnt[t] = 0; lcnt[t + 256] = 0;
        __syncthreads();
        unsigned int rec[8];
        int bk[8];
#pragma unroll
        for (int u = 0; u < 8; ++u) {
            int e = e0 + u * 256 + t;
            if (e < E) {
                int src = ei[e];
                int dst = ei[E + e];
                int et  = ea[2 * e];
                int ed  = ea[2 * e + 1];
                rec[u] = (unsigned int)src | ((unsigned int)et << 16)
                       | ((unsigned int)ed << 18)
                       | ((unsigned int)(dst & 127) << 20);
                bk[u] = dst >> 7;
                atomicAdd(&lcnt[bk[u]], 1);
            } else bk[u] = -1;
        }
        __syncthreads();
        for (int j = t; j < 512; j += 256) {  // reserve cursors
            int c = lcnt[j];
            lcnt[j] = (c > 0) ? atomicAdd(&gcur[j], c) : 0;
        }
        __syncthreads();
#pragma unroll
        for (int u = 0; u < 8; ++u) {
            if (bk[u] >= 0) {
                int pos = atomicAdd(&lcnt[bk[u]], 1);
                if (pos < BCAP) binned[(size_t)bk[u] * BCAP + pos] = rec[u];
            }
        }
        return;
    }

    // ---- px blocks: 4 floats -> half2x2 per thread, mask folded in ----
    int idx = blockIdx.x * 256 + t;           // over n*32
    if (idx < n * 32) {
        int node = idx >> 5;
        bool msk = (bm[node >> 5] >> (node & 31)) & 1u;
        float a = prelu_a[0];
        float4 v = *(const float4*)((const float*)x + (size_t)idx * 4);
        v.x = v.x > 0.f ? v.x : a * v.x;
        v.y = v.y > 0.f ? v.y : a * v.y;
        v.z = v.z > 0.f ? v.z : a * v.z;
        v.w = v.w > 0.f ? v.w : a * v.w;
        uint2 o;
        if (msk) { o.x = 0u; o.y = 0u; }
        else {
            __half2 lo = __floats2half2_rn(v.x, v.y);
            __half2 hi = __floats2half2_rn(v.z, v.w);
            o.x = *(unsigned int*)&lo;
            o.y = *(unsigned int*)&hi;
        }
        px16u2[idx] = o;
    }
}

// ---- K_aggb: one block per 128-dst bucket; fp32 LDS accumulate -----------
__global__ __launch_bounds__(256, 2) void k_aggb(const unsigned int* __restrict__ px_u,
                                                 const uint2* __restrict__ px2,
                                                 const unsigned int* __restrict__ binned,
                                                 const int* __restrict__ gcur,
                                                 ull* __restrict__ cnt64,
                                                 uint2* __restrict__ agg2,
                                                 int n)
{
    __shared__ float accf[128 * 128];         // 64 KB
    __shared__ ull lc[128];                   // 1 KB
    int b = blockIdx.x, t = threadIdx.x;
    for (int i = t; i < 128 * 32; i += 256)   // zero accf (float4)
        *(f32x4*)(accf + i * 4) = f32x4{0.f, 0.f, 0.f, 0.f};
    if (t < 128) lc[t] = 0;
    __syncthreads();

    int mcnt = min(gcur[b], BCAP);
    const unsigned int* bp = binned + (size_t)b * BCAP;
    int lane = t & 63, w = t >> 6;

    for (int i0 = w * 8; i0 < mcnt; i0 += 32) {
        int cnt = min(8, mcnt - i0);
        if (cnt == 8) {
            unsigned int rec[8], v[8];
#pragma unroll
            for (int k = 0; k < 8; ++k) rec[k] = bp[i0 + k];
#pragma unroll
            for (int k = 0; k < 8; ++k)
                v[k] = px_u[((size_t)(rec[k] & 0xFFFF) << 6) + lane];
#pragma unroll
            for (int k = 0; k < 8; ++k) {
                int dl = (rec[k] >> 20) & 127;
                if (lane == 0) {
                    int et = (rec[k] >> 16) & 3, ed = (rec[k] >> 18) & 3;
                    atomicAdd(&lc[dl],
                              (1ULL << (10 * et)) | (1ULL << (30 + 10 * ed)));
                }
                float2 f = __half22float2(*(__half2*)&v[k]);
                unsafeAtomicAdd(&accf[(dl << 7) + (lane << 1)],     f.x);
                unsafeAtomicAdd(&accf[(dl << 7) + (lane << 1) + 1], f.y);
            }
        } else {
            for (int k = 0; k < cnt; ++k) {
                unsigned int rec = bp[i0 + k];
                unsigned int v = px_u[((size_t)(rec & 0xFFFF) << 6) + lane];
                int dl = (rec >> 20) & 127;
                if (lane == 0) {
                    int et = (rec >> 16) & 3, ed = (rec >> 18) & 3;
                    atomicAdd(&lc[dl],
                              (1ULL << (10 * et)) | (1ULL << (30 + 10 * ed)));
                }
                float2 f = __half22float2(*(__half2*)&v);
                unsafeAtomicAdd(&accf[(dl << 7) + (lane << 1)],     f.x);
                unsafeAtomicAdd(&accf[(dl << 7) + (lane << 1) + 1], f.y);
            }
        }
    }
    __syncthreads();

    int dstbase = b << 7;
    if (t < 128 && dstbase + t < n) cnt64[dstbase + t] = lc[t];
    for (int i = t; i < 128 * 32; i += 256) { // row r, uint2 slot q
        int r = i >> 5, q = i & 31;
        int node = dstbase + r;
        if (node < n) {
            uint2 sv = px2[(size_t)node * 32 + q];       // self loop
            float2 sA = __half22float2(*(__half2*)&sv.x);
            float2 sB = __half22float2(*(__half2*)&sv.y);
            const float* ap = accf + (r << 7) + (q << 2);
            __half2 oL = __floats2half2_rn(ap[0] + sA.x, ap[1] + sA.y);
            __half2 oH = __floats2half2_rn(ap[2] + sB.x, ap[3] + sB.y);
            uint2 o;
            o.x = *(unsigned int*)&oL;
            o.y = *(unsigned int*)&oH;
            __builtin_nontemporal_store(*(ull*)&o,
                                        (ull*)(agg2 + (size_t)node * 32 + q));
        }
    }
}

// ---- K5: hid16 = relu(agg16 @ Wc^T + S + counts.T/U), MFMA + LDS-W -------
__global__ __launch_bounds__(256, 2) void k_mlp1(const __half* __restrict__ agg16,
                                                 const __half* __restrict__ Wc16,
                                                 const float* __restrict__ tabs,
                                                 const ull* __restrict__ cnt64,
                                                 __half* __restrict__ hid16, int n)
{
    __shared__ __half Wl[256 * 136];          // stride 272B (69.6 KB)
    __shared__ float tl[7 * 256];             // 7 KB
    int t = threadIdx.x;
    for (int c = t; c < 4096; c += 256) {     // stage Wc (256x128 halves)
        int row = c >> 4, slot = c & 15;
        *(uint4*)((char*)Wl + row * 272 + slot * 16) =
            *(const uint4*)((const char*)Wc16 + (size_t)c * 16);
    }
    for (int c = t; c < 1792; c += 256) tl[c] = tabs[c];
    __syncthreads();
    int lane = t & 63, wid = t >> 6;
    int rowbase = blockIdx.x * 128 + wid * 32;
    int mr0 = min(rowbase + (lane & 15), n - 1);
    int mr1 = min(rowbase + 16 + (lane & 15), n - 1);
    int kg = (lane >> 4) * 8, slotb = lane >> 4;
    f32x4 acc[32] = {};
#pragma unroll
    for (int ks = 0; ks < 4; ++ks) {
        half8 a0 = *(const half8*)(agg16 + ((size_t)mr0 << 7) + ks * 32 + kg);
        half8 a1 = *(const half8*)(agg16 + ((size_t)mr1 << 7) + ks * 32 + kg);
        const char* wp = (const char*)Wl + (size_t)(lane & 15) * 272
                       + (ks * 4 + slotb) * 16;
#pragma unroll
        for (int ct = 0; ct < 16; ++ct) {
            half8 bf = *(const half8*)(wp + ct * (16 * 272));
            acc[ct * 2]     = MFMA16(a0, bf, acc[ct * 2]);
            acc[ct * 2 + 1] = MFMA16(a1, bf, acc[ct * 2 + 1]);
        }
    }
    // epilogue: + S + c0*T0+c1*T1+c2*T2 + d0*U0+d1*U1+d2*U2, relu, fp16
#pragma unroll
    for (int h = 0; h < 2; ++h) {
        float cf[4][6];
        int nodes[4];
#pragma unroll
        for (int r = 0; r < 4; ++r) {
            int node = rowbase + h * 16 + ((lane >> 4) << 2) + r;
            nodes[r] = node;
            ull c = (node < n) ? cnt64[node] : 0ULL;
            cf[r][0] = (float)(c & 1023);
            cf[r][1] = (float)((c >> 10) & 1023);
            cf[r][2] = (float)((c >> 20) & 1023);
            cf[r][3] = (float)((c >> 30) & 1023);
            cf[r][4] = (float)((c >> 40) & 1023);
            cf[r][5] = (float)((c >> 50) & 1023);
        }
#pragma unroll
        for (int ct = 0; ct < 16; ++ct) {
            int col = (ct << 4) + (lane & 15);
            float S  = tl[col];
            float T0 = tl[256 + col],  T1 = tl[512 + col],  T2 = tl[768 + col];
            float U0 = tl[1024 + col], U1 = tl[1280 + col], U2 = tl[1536 + col];
#pragma unroll
            for (int r = 0; r < 4; ++r) {
                if (nodes[r] < n) {
                    float v = acc[ct * 2 + h][r] + S;
                    v = fmaf(cf[r][0], T0, v);
                    v = fmaf(cf[r][1], T1, v);
                    v = fmaf(cf[r][2], T2, v);
                    v = fmaf(cf[r][3], U0, v);
                    v = fmaf(cf[r][4], U1, v);
                    v = fmaf(cf[r][5], U2, v);
                    hid16[((size_t)nodes[r] << 8) + col] =
                        __float2half(v > 0.f ? v : 0.f);
                }
            }
        }
    }
}

// ---- K6: out = hid16 @ W2^T + b2, MFMA + LDS-W ---------------------------
__global__ __launch_bounds__(256, 2) void k_mlp2(const __half* __restrict__ hid16,
                                                 const __half* __restrict__ W2_16p,
                                                 const float* __restrict__ b2,
                                                 float* __restrict__ out, int n)
{
    __shared__ __half W2l[128 * 264];         // stride 528B (67.6 KB)
    int t = threadIdx.x;
    for (int c = t; c < 4096; c += 256) {     // stage W2p (128x256 halves)
        int row = c >> 5, slot = c & 31;
        *(uint4*)((char*)W2l + row * 528 + slot * 16) =
            *(const uint4*)((const char*)W2_16p + (size_t)c * 16);
    }
    __syncthreads();
    int lane = t & 63, wid = t >> 6;
    int rowbase = blockIdx.x * 128 + wid * 32;
    int mr0 = min(rowbase + (lane & 15), n - 1);
    int mr1 = min(rowbase + 16 + (lane & 15), n - 1);
    int kg = (lane >> 4) * 8, slotb = lane >> 4;
    f32x4 acc[16] = {};
#pragma unroll
    for (int ks = 0; ks < 8; ++ks) {
        half8 a0 = *(const half8*)(hid16 + ((size_t)mr0 << 8) + ks * 32 + kg);
        half8 a1 = *(const half8*)(hid16 + ((size_t)mr1 << 8) + ks * 32 + kg);
        const char* wp = (const char*)W2l + (size_t)(lane & 15) * 528
                       + (ks * 4 + slotb) * 16;
#pragma unroll
        for (int ct = 0; ct < 8; ++ct) {
            half8 bf = *(const half8*)(wp + ct * (16 * 528));
            acc[ct * 2]     = MFMA16(a0, bf, acc[ct * 2]);
            acc[ct * 2 + 1] = MFMA16(a1, bf, acc[ct * 2 + 1]);
        }
    }
#pragma unroll
    for (int ct = 0; ct < 8; ++ct) {
        int col = (ct << 4) + (lane & 15);
        if (col >= 119) continue;
        float bb = b2[col];
#pragma unroll
        for (int h = 0; h < 2; ++h)
#pragma unroll
            for (int r = 0; r < 4; ++r) {
                int node = rowbase + h * 16 + ((lane >> 4) << 2) + r;
                if (node < n)
                    out[(size_t)node * 119 + col] = acc[ct * 2 + h][r] + bb;
            }
    }
}

extern "C" void kernel_launch(void* const* d_in, const int* in_sizes, int n_in,
                              void* d_out, int out_size, void* d_ws, size_t ws_size,
                              hipStream_t stream)
{
    const float* x    = (const float*)d_in[0];
    const int*   ei   = (const int*)d_in[1];    // [2,E]
    const int*   ea   = (const int*)d_in[2];    // [E,2]
    const int*   midx = (const int*)d_in[3];    // [NM]
    const float* pa   = (const float*)d_in[4];  // scalar
    const float* Wen  = (const float*)d_in[5];  // [128,128]
    const float* emb1 = (const float*)d_in[6];  // [6,128]
    const float* emb2 = (const float*)d_in[7];  // [3,128]
    const float* W1   = (const float*)d_in[8];  // [256,128]
    const float* b1   = (const float*)d_in[9];  // [256]
    const float* W2   = (const float*)d_in[10]; // [119,256]
    const float* b2   = (const float*)d_in[11]; // [119]
    float* out = (float*)d_out;

    int n  = in_sizes[0] / 128;
    int E  = in_sizes[1] / 2;
    int nm = in_sizes[3];
    int nb = (n + 127) >> 7;                    // 391 buckets (<=512)

    char* ws = (char*)d_ws;
    size_t HB = (size_t)n * 128 * 2;            // 12.8 MB (fp16 n x 128)
    __half* agg16 = (__half*)ws;                // [0, HB)
    __half* px16  = (__half*)(ws + HB);         // [HB, 2HB)
    __half* hid16 = (__half*)(ws + 2 * HB);     // [2HB, 4HB)
    char* p = ws + 4 * HB;
    __half* Wc16   = (__half*)p;  p += 256 * 128 * 2;
    __half* W2_16p = (__half*)p;  p += 128 * 256 * 2;
    float*  tabs   = (float*)p;   p += 7 * 256 * 4;
    ull* cnt64  = (ull*)p;        p += (size_t)n * 8;
    int* gcur   = (int*)p;        p += 512 * 4;
    unsigned int* bm = (unsigned int*)p;  p += 2048 * 4;
    unsigned int* binned = (unsigned int*)p;
    p += (size_t)nb * BCAP * 4;                 // ~4 MB; total ~56 MB

    int nbPx  = (n * 32 + 255) / 256;           // 6250
    int nbBin = (E + EPB - 1) / EPB;            // 391

    k_wconv<<<194, 256, 0, stream>>>(Wen, W1, W2, b1, emb1, emb2, midx,
                                     Wc16, W2_16p, tabs, gcur, bm, n, E, nm);
    k_pre  <<<nbPx + nbBin, 256, 0, stream>>>(x, pa, bm, (uint2*)px16, ei, ea,
                                              gcur, binned, n, E, nbPx, nbBin);
    k_aggb <<<nb, 256, 0, stream>>>((const unsigned int*)px16,
                                    (const uint2*)px16, binned, gcur,
                                    cnt64, (uint2*)agg16, n);
    k_mlp1 <<<(n + 127) / 128, 256, 0, stream>>>(agg16, Wc16, tabs, cnt64,
                                                 hid16, n);
    k_mlp2 <<<(n + 127) / 128, 256, 0, stream>>>(hid16, W2_16p, b2, out, n);
}

// Round 15
// 128.946 us; speedup vs baseline: 6.1018x; 6.1018x over previous
//
#include <hip/hip_runtime.h>
#include <hip/hip_fp16.h>

// ---------------------------------------------------------------------------
// GNNDecoder, Wenc folded past the aggregation (linearity):
//   px16 = fp16(prelu(x)) ; px16[mask]=0 (mask folded into px phase, bitmap)
//   agg16[dst] = px16[dst] + sum_{edges->dst} px16[src]        (pure gather)
//   hid16 = relu( agg16 @ Wc^T + S + c*T + d*U )  (Wc=W1@Wenc, tabs=emb@W1^T)
//   out = hid16 @ W2^T + b2
// N=50000, E=800000, D=128, DFF=256, OUT=119
//
// GEMMs: v_mfma_f32_16x16x32_f16, fp32 accum, weights LDS-staged (row stride
// 272B/528B == 4 mod 32 dwords -> 2-way bank aliasing, free), 2 blocks/CU.
// R11 lesson: fusing mlp1+mlp2 (141KB LDS -> 1 block/CU) exposed staging
// latency -- occupancy beats the 51MB hid round-trip.
// R14 lesson: direct LDS-atomic aggregation (64KB accf) serializes on bank
// aliasing x row contention AND kills the occupancy that hides gather
// latency (709us) -- the sort+register-gather structure is the right one.
// Aggregation: 2-level bucketed counting sort; binning via per-block
// LDS-aggregated cursor reservation (R6 lesson). k_agg is queue/latency
// bound at ~7cyc/line issue; 8-deep unroll, nontemporal only on read-once
// streams (sorted); agg2 stored normally so k_mlp1 re-reads hit L2/L3.
// ---------------------------------------------------------------------------

typedef unsigned long long ull;
typedef _Float16 half8 __attribute__((ext_vector_type(8)));
typedef float    f32x4 __attribute__((ext_vector_type(4)));

#define MFMA16(a, b, c) __builtin_amdgcn_mfma_f32_16x16x32_f16(a, b, c, 0, 0, 0)
#define BCAP 4608   // bucket capacity (mean 4096, ~8 sigma slack)
#define EPB  2048   // edges per binning block (8 per thread)

// ---- K_wconv: Wc = W1@Wenc (fp16), W2 pad-convert, emb@W1^T tables,
// ----          gcur zero, off[n]=E, mask bitmap  (194 blocks) --------------
__global__ __launch_bounds__(256) void k_wconv(const float* __restrict__ Wen,
                                               const float* __restrict__ W1,
                                               const float* __restrict__ W2,
                                               const float* __restrict__ b1,
                                               const float* __restrict__ emb1,
                                               const float* __restrict__ emb2,
                                               const int* __restrict__ midx,
                                               __half* __restrict__ Wc16,
                                               __half* __restrict__ W2_16p,
                                               float* __restrict__ tabs,
                                               int* __restrict__ gcur,
                                               int* __restrict__ off,
                                               unsigned int* __restrict__ bm,
                                               int n, int E, int nm)
{
    int b = blockIdx.x, t = threadIdx.x;
    if (b < 128) {                            // Wc rows 2b, 2b+1
        __shared__ float We[128 * 128];
        for (int i = t; i < 4096; i += 256) {
            int j = i >> 5, k4 = (i & 31) << 2;
            *(float4*)(We + (j << 7) + k4) = *(const float4*)(Wen + (j << 7) + k4);
        }
        __syncthreads();
        int r = (b << 1) | (t >> 7);
        int k = t & 127;
        const float* w1r = W1 + ((size_t)r << 7);
        float acc = 0.f;
#pragma unroll 8
        for (int j = 0; j < 128; ++j)
            acc = fmaf(w1r[j], We[(j << 7) + k], acc);
        Wc16[(r << 7) + k] = __float2half(acc);
    } else if (b < 192) {                     // W2 pad-convert (2 elems/thread)
#pragma unroll
        for (int u = 0; u < 2; ++u) {
            int i = (b - 128) * 512 + u * 256 + t;    // 0..32767
            int r = i >> 8;
            W2_16p[i] = (r < 119) ? __float2half(W2[i]) : __half(0.0f);
        }
    } else if (b == 192) {                    // S,T0..2,U0..2 tables
        int col = t;
        const float* w1r = W1 + ((size_t)col << 7);
        float s = 0.f, t0 = 0.f, t1 = 0.f, t2 = 0.f,
              u0 = 0.f, u1 = 0.f, u2 = 0.f;
        for (int j = 0; j < 128; ++j) {
            float w = w1r[j];
            s  = fmaf(emb1[512 + j] + emb2[j], w, s);
            t0 = fmaf(emb1[j],        w, t0);
            t1 = fmaf(emb1[128 + j],  w, t1);
            t2 = fmaf(emb1[256 + j],  w, t2);
            u0 = fmaf(emb2[j],        w, u0);
            u1 = fmaf(emb2[128 + j],  w, u1);
            u2 = fmaf(emb2[256 + j],  w, u2);
        }
        tabs[col]            = s + b1[col];
        tabs[256 + col]      = t0;
        tabs[512 + col]      = t1;
        tabs[768 + col]      = t2;
        tabs[1024 + col]     = u0;
        tabs[1280 + col]     = u1;
        tabs[1536 + col]     = u2;
    } else {                                  // b == 193: gcur, off[n], bitmap
        gcur[t] = 0;
        if (t == 0) off[n] = E;
        int nw = (n + 31) >> 5;
        for (int i = t; i < nw; i += 256) bm[i] = 0u;
        __syncthreads();
        for (int m = t; m < nm; m += 256) {
            int node = midx[m];
            atomicOr(&bm[node >> 5], 1u << (node & 31));
        }
    }
}

// ---- K_pre: {px16 = fp16(prelu(x)), mask via bitmap} + {edge binning} ----
__global__ __launch_bounds__(256) void k_pre(const float* __restrict__ x,
                                             const float* __restrict__ prelu_a,
                                             const unsigned int* __restrict__ bm,
                                             uint2* __restrict__ px16u2,
                                             const int* __restrict__ ei,
                                             const int* __restrict__ ea,
                                             int* __restrict__ gcur,
                                             unsigned int* __restrict__ binned,
                                             int n, int E, int nbPx, int nbBin)
{
    __shared__ int lcnt[256];
    int t = threadIdx.x;

    if ((int)blockIdx.x >= nbPx) {            // ---- binning blocks ----
        int b = blockIdx.x - nbPx;
        int e0 = b * EPB;
        lcnt[t] = 0;
        __syncthreads();
        unsigned int rec[8];
        int bk[8];
#pragma unroll
        for (int u = 0; u < 8; ++u) {
            int e = e0 + u * 256 + t;
            if (e < E) {
                int src = ei[e];
                int dst = ei[E + e];
                int et  = ea[2 * e];
                int ed  = ea[2 * e + 1];
                rec[u] = (unsigned int)src | ((unsigned int)et << 17)
                       | ((unsigned int)ed << 19)
                       | ((unsigned int)(dst & 255) << 21);
                bk[u] = dst >> 8;
                atomicAdd(&lcnt[bk[u]], 1);
            } else bk[u] = -1;
        }
        __syncthreads();
        int c = lcnt[t];                      // only thread t touches lcnt[t]
        lcnt[t] = (c > 0) ? atomicAdd(&gcur[t], c) : 0;   // now a cursor
        __syncthreads();
#pragma unroll
        for (int u = 0; u < 8; ++u) {
            if (bk[u] >= 0) {
                int pos = atomicAdd(&lcnt[bk[u]], 1);
                if (pos < BCAP) binned[(size_t)bk[u] * BCAP + pos] = rec[u];
            }
        }
        return;
    }

    // ---- px blocks: 4 floats -> half2x2 per thread, mask folded in ----
    int idx = blockIdx.x * 256 + t;           // over n*32
    if (idx < n * 32) {
        int node = idx >> 5;
        bool msk = (bm[node >> 5] >> (node & 31)) & 1u;
        float a = prelu_a[0];
        float4 v = *(const float4*)((const float*)x + (size_t)idx * 4);
        v.x = v.x > 0.f ? v.x : a * v.x;
        v.y = v.y > 0.f ? v.y : a * v.y;
        v.z = v.z > 0.f ? v.z : a * v.z;
        v.w = v.w > 0.f ? v.w : a * v.w;
        uint2 o;
        if (msk) { o.x = 0u; o.y = 0u; }
        else {
            __half2 lo = __floats2half2_rn(v.x, v.y);
            __half2 hi = __floats2half2_rn(v.z, v.w);
            o.x = *(unsigned int*)&lo;
            o.y = *(unsigned int*)&hi;
        }
        px16u2[idx] = o;
    }
}

// ---- K_bucket: 2 blocks per bucket {LDS hist, scan -> off, scatter half} -
__global__ __launch_bounds__(256) void k_bucket(const unsigned int* __restrict__ binned,
                                                const int* __restrict__ gcur,
                                                ull* __restrict__ cnt64,
                                                int* __restrict__ off,
                                                int* __restrict__ sorted,
                                                int n, int nb)
{
    __shared__ ull lc[256];
    __shared__ int sg[2][256];
    __shared__ int curs[256];
    int b = blockIdx.x >> 1, half = blockIdx.x & 1;
    int t = threadIdx.x;

    int gv = (t < nb) ? min(gcur[t], BCAP) : 0;
    sg[0][t] = gv;
    lc[t] = 0;
    __syncthreads();
    int cb = 0;
    for (int d = 1; d < 256; d <<= 1) {
        int v = sg[cb][t];
        if (t >= d) v += sg[cb][t - d];
        sg[cb ^ 1][t] = v;
        cb ^= 1;
        __syncthreads();
    }
    int ebase = (b == 0) ? 0 : sg[cb][b - 1];
    int mcnt = min(gcur[b], BCAP);
    __syncthreads();

    const unsigned int* bp = binned + (size_t)b * BCAP;
    for (int i = t; i < mcnt; i += 256) {
        unsigned int rec = bp[i];
        int dl = (rec >> 21) & 255;
        int et = (rec >> 17) & 3;
        int ed = (rec >> 19) & 3;
        atomicAdd(&lc[dl], (1ULL << (10 * et)) | (1ULL << (30 + 10 * ed)));
    }
    __syncthreads();

    ull c = lc[t];
    int deg = (int)((c & 1023) + ((c >> 10) & 1023) + ((c >> 20) & 1023));
    sg[0][t] = deg;
    __syncthreads();
    cb = 0;
    for (int d = 1; d < 256; d <<= 1) {
        int v = sg[cb][t];
        if (t >= d) v += sg[cb][t - d];
        sg[cb ^ 1][t] = v;
        cb ^= 1;
        __syncthreads();
    }
    int loc = sg[cb][t] - deg;
    int dst = (b << 8) + t;
    if (dst < n && (t >> 7) == half) {        // this block owns half the dsts
        cnt64[dst] = c;
        off[dst]   = ebase + loc;
    }
    curs[t] = ebase + loc;
    __syncthreads();

    for (int i = t; i < mcnt; i += 256) {
        unsigned int rec = bp[i];
        int dl = (rec >> 21) & 255;
        if ((dl >> 7) != half) continue;      // other block scatters it
        int p = atomicAdd(&curs[dl], 1);
        sorted[p] = (int)(rec & 0x1FFFF);
    }
}

// ---- K_agg: 2 nodes per wave, fp16 gather-sum, 8-deep MLP unroll ---------
__global__ __launch_bounds__(256) void k_agg(const uint2* __restrict__ px2,
                                             const int* __restrict__ off,
                                             const int* __restrict__ sorted,
                                             uint2* __restrict__ agg2, int n)
{
    int t = threadIdx.x;
    int l32 = t & 31;
    int node = blockIdx.x * 8 + (t >> 5);
    if (node >= n) return;

    // self loop in fp32 base
    uint2 hv = px2[(size_t)node * 32 + l32];
    float2 hA = __half22float2(*(__half2*)&hv.x);
    float2 hB = __half22float2(*(__half2*)&hv.y);
    float4 base = make_float4(hA.x, hA.y, hB.x, hB.y);

    __half2 aL[4], aH[4];
#pragma unroll
    for (int u = 0; u < 4; ++u) { aL[u] = __half2(); aH[u] = __half2(); }
    int i = off[node], e = off[node + 1];

    // 8-deep: 8 independent gathers in flight per node stream
    for (; i + 7 < e; i += 8) {
        int s[8];
        uint2 v[8];
#pragma unroll
        for (int k = 0; k < 8; ++k)
            s[k] = __builtin_nontemporal_load(sorted + i + k);
#pragma unroll
        for (int k = 0; k < 8; ++k)
            v[k] = px2[(size_t)s[k] * 32 + l32];
#pragma unroll
        for (int k = 0; k < 8; ++k) {
            aL[k & 3] = __hadd2(aL[k & 3], *(__half2*)&v[k].x);
            aH[k & 3] = __hadd2(aH[k & 3], *(__half2*)&v[k].y);
        }
    }
    // 4-deep tail
    for (; i + 3 < e; i += 4) {
        int s[4];
        uint2 v[4];
#pragma unroll
        for (int k = 0; k < 4; ++k)
            s[k] = __builtin_nontemporal_load(sorted + i + k);
#pragma unroll
        for (int k = 0; k < 4; ++k)
            v[k] = px2[(size_t)s[k] * 32 + l32];
#pragma unroll
        for (int k = 0; k < 4; ++k) {
            aL[k] = __hadd2(aL[k], *(__half2*)&v[k].x);
            aH[k] = __hadd2(aH[k], *(__half2*)&v[k].y);
        }
    }
    for (; i < e; ++i) {
        int s0 = __builtin_nontemporal_load(sorted + i);
        uint2 v0 = px2[(size_t)s0 * 32 + l32];
        aL[0] = __hadd2(aL[0], *(__half2*)&v0.x);
        aH[0] = __hadd2(aH[0], *(__half2*)&v0.y);
    }
#pragma unroll
    for (int u = 0; u < 4; ++u) {
        float2 fL = __half22float2(aL[u]);
        float2 fH = __half22float2(aH[u]);
        base.x += fL.x; base.y += fL.y;
        base.z += fH.x; base.w += fH.y;
    }
    __half2 oL = __floats2half2_rn(base.x, base.y);
    __half2 oH = __floats2half2_rn(base.z, base.w);
    uint2 o;
    o.x = *(unsigned int*)&oL;
    o.y = *(unsigned int*)&oH;
    agg2[(size_t)node * 32 + l32] = o;        // normal store: mlp1 re-reads it
}

// ---- K5: hid16 = relu(agg16 @ Wc^T + S + counts.T/U), MFMA + LDS-W -------
__global__ __launch_bounds__(256, 2) void k_mlp1(const __half* __restrict__ agg16,
                                                 const __half* __restrict__ Wc16,
                                                 const float* __restrict__ tabs,
                                                 const ull* __restrict__ cnt64,
                                                 __half* __restrict__ hid16, int n)
{
    __shared__ __half Wl[256 * 136];          // stride 272B (69.6 KB)
    __shared__ float tl[7 * 256];             // 7 KB
    int t = threadIdx.x;
    for (int c = t; c < 4096; c += 256) {     // stage Wc (256x128 halves)
        int row = c >> 4, slot = c & 15;
        *(uint4*)((char*)Wl + row * 272 + slot * 16) =
            *(const uint4*)((const char*)Wc16 + (size_t)c * 16);
    }
    for (int c = t; c < 1792; c += 256) tl[c] = tabs[c];
    __syncthreads();
    int lane = t & 63, wid = t >> 6;
    int rowbase = blockIdx.x * 128 + wid * 32;
    int mr0 = min(rowbase + (lane & 15), n - 1);
    int mr1 = min(rowbase + 16 + (lane & 15), n - 1);
    int kg = (lane >> 4) * 8, slotb = lane >> 4;
    f32x4 acc[32] = {};
#pragma unroll
    for (int ks = 0; ks < 4; ++ks) {
        half8 a0 = *(const half8*)(agg16 + ((size_t)mr0 << 7) + ks * 32 + kg);
        half8 a1 = *(const half8*)(agg16 + ((size_t)mr1 << 7) + ks * 32 + kg);
        const char* wp = (const char*)Wl + (size_t)(lane & 15) * 272
                       + (ks * 4 + slotb) * 16;
#pragma unroll
        for (int ct = 0; ct < 16; ++ct) {
            half8 bf = *(const half8*)(wp + ct * (16 * 272));
            acc[ct * 2]     = MFMA16(a0, bf, acc[ct * 2]);
            acc[ct * 2 + 1] = MFMA16(a1, bf, acc[ct * 2 + 1]);
        }
    }
    // epilogue: + S + c0*T0+c1*T1+c2*T2 + d0*U0+d1*U1+d2*U2, relu, fp16
#pragma unroll
    for (int h = 0; h < 2; ++h) {
        float cf[4][6];
        int nodes[4];
#pragma unroll
        for (int r = 0; r < 4; ++r) {
            int node = rowbase + h * 16 + ((lane >> 4) << 2) + r;
            nodes[r] = node;
            ull c = (node < n) ? cnt64[node] : 0ULL;
            cf[r][0] = (float)(c & 1023);
            cf[r][1] = (float)((c >> 10) & 1023);
            cf[r][2] = (float)((c >> 20) & 1023);
            cf[r][3] = (float)((c >> 30) & 1023);
            cf[r][4] = (float)((c >> 40) & 1023);
            cf[r][5] = (float)((c >> 50) & 1023);
        }
#pragma unroll
        for (int ct = 0; ct < 16; ++ct) {
            int col = (ct << 4) + (lane & 15);
            float S  = tl[col];
            float T0 = tl[256 + col],  T1 = tl[512 + col],  T2 = tl[768 + col];
            float U0 = tl[1024 + col], U1 = tl[1280 + col], U2 = tl[1536 + col];
#pragma unroll
            for (int r = 0; r < 4; ++r) {
                if (nodes[r] < n) {
                    float v = acc[ct * 2 + h][r] + S;
                    v = fmaf(cf[r][0], T0, v);
                    v = fmaf(cf[r][1], T1, v);
                    v = fmaf(cf[r][2], T2, v);
                    v = fmaf(cf[r][3], U0, v);
                    v = fmaf(cf[r][4], U1, v);
                    v = fmaf(cf[r][5], U2, v);
                    hid16[((size_t)nodes[r] << 8) + col] =
                        __float2half(v > 0.f ? v : 0.f);
                }
            }
        }
    }
}

// ---- K6: out = hid16 @ W2^T + b2, MFMA + LDS-W ---------------------------
__global__ __launch_bounds__(256, 2) void k_mlp2(const __half* __restrict__ hid16,
                                                 const __half* __restrict__ W2_16p,
                                                 const float* __restrict__ b2,
                                                 float* __restrict__ out, int n)
{
    __shared__ __half W2l[128 * 264];         // stride 528B (67.6 KB)
    int t = threadIdx.x;
    for (int c = t; c < 4096; c += 256) {     // stage W2p (128x256 halves)
        int row = c >> 5, slot = c & 31;
        *(uint4*)((char*)W2l + row * 528 + slot * 16) =
            *(const uint4*)((const char*)W2_16p + (size_t)c * 16);
    }
    __syncthreads();
    int lane = t & 63, wid = t >> 6;
    int rowbase = blockIdx.x * 128 + wid * 32;
    int mr0 = min(rowbase + (lane & 15), n - 1);
    int mr1 = min(rowbase + 16 + (lane & 15), n - 1);
    int kg = (lane >> 4) * 8, slotb = lane >> 4;
    f32x4 acc[16] = {};
#pragma unroll
    for (int ks = 0; ks < 8; ++ks) {
        half8 a0 = *(const half8*)(hid16 + ((size_t)mr0 << 8) + ks * 32 + kg);
        half8 a1 = *(const half8*)(hid16 + ((size_t)mr1 << 8) + ks * 32 + kg);
        const char* wp = (const char*)W2l + (size_t)(lane & 15) * 528
                       + (ks * 4 + slotb) * 16;
#pragma unroll
        for (int ct = 0; ct < 8; ++ct) {
            half8 bf = *(const half8*)(wp + ct * (16 * 528));
            acc[ct * 2]     = MFMA16(a0, bf, acc[ct * 2]);
            acc[ct * 2 + 1] = MFMA16(a1, bf, acc[ct * 2 + 1]);
        }
    }
#pragma unroll
    for (int ct = 0; ct < 8; ++ct) {
        int col = (ct << 4) + (lane & 15);
        if (col >= 119) continue;
        float bb = b2[col];
#pragma unroll
        for (int h = 0; h < 2; ++h)
#pragma unroll
            for (int r = 0; r < 4; ++r) {
                int node = rowbase + h * 16 + ((lane >> 4) << 2) + r;
                if (node < n)
                    out[(size_t)node * 119 + col] = acc[ct * 2 + h][r] + bb;
            }
    }
}

extern "C" void kernel_launch(void* const* d_in, const int* in_sizes, int n_in,
                              void* d_out, int out_size, void* d_ws, size_t ws_size,
                              hipStream_t stream)
{
    const float* x    = (const float*)d_in[0];
    const int*   ei   = (const int*)d_in[1];    // [2,E]
    const int*   ea   = (const int*)d_in[2];    // [E,2]
    const int*   midx = (const int*)d_in[3];    // [NM]
    const float* pa   = (const float*)d_in[4];  // scalar
    const float* Wen  = (const float*)d_in[5];  // [128,128]
    const float* emb1 = (const float*)d_in[6];  // [6,128]
    const float* emb2 = (const float*)d_in[7];  // [3,128]
    const float* W1   = (const float*)d_in[8];  // [256,128]
    const float* b1   = (const float*)d_in[9];  // [256]
    const float* W2   = (const float*)d_in[10]; // [119,256]
    const float* b2   = (const float*)d_in[11]; // [119]
    float* out = (float*)d_out;

    int n  = in_sizes[0] / 128;
    int E  = in_sizes[1] / 2;
    int nm = in_sizes[3];
    int nb = (n + 255) >> 8;                    // 196 buckets (<=256)

    char* ws = (char*)d_ws;
    size_t HB = (size_t)n * 128 * 2;            // 12.8 MB (fp16 n x 128)
    __half* agg16 = (__half*)ws;                // [0, HB)
    __half* px16  = (__half*)(ws + HB);         // [HB, 2HB)
    __half* hid16 = (__half*)(ws + 2 * HB);     // [2HB, 4HB)
    char* p = ws + 4 * HB;
    __half* Wc16   = (__half*)p;  p += 256 * 128 * 2;
    __half* W2_16p = (__half*)p;  p += 128 * 256 * 2;
    float*  tabs   = (float*)p;   p += 7 * 256 * 4;
    ull* cnt64  = (ull*)p;        p += (size_t)n * 8;
    int* gcur   = (int*)p;        p += 256 * 4;
    unsigned int* bm = (unsigned int*)p;  p += 2048 * 4;
    int* off    = (int*)p;        p += (size_t)(n + 1) * 4;
    int* sorted = (int*)p;        p += (size_t)E * 4;
    unsigned int* binned = (unsigned int*)p;
    p += (size_t)nb * BCAP * 4;                 // total ~59 MB

    int nbPx  = (n * 32 + 255) / 256;           // 6250
    int nbBin = (E + EPB - 1) / EPB;            // 391

    k_wconv<<<194, 256, 0, stream>>>(Wen, W1, W2, b1, emb1, emb2, midx,
                                     Wc16, W2_16p, tabs, gcur, off, bm,
                                     n, E, nm);
    k_pre  <<<nbPx + nbBin, 256, 0, stream>>>(x, pa, bm, (uint2*)px16, ei, ea,
                                              gcur, binned, n, E, nbPx, nbBin);
    k_bucket<<<nb * 2, 256, 0, stream>>>(binned, gcur, cnt64, off, sorted, n, nb);
    k_agg  <<<(n + 7) / 8, 256, 0, stream>>>((const uint2*)px16, off, sorted,
                                             (uint2*)agg16, n);
    k_mlp1 <<<(n + 127) / 128, 256, 0, stream>>>(agg16, Wc16, tabs, cnt64,
                                                 hid16, n);
    k_mlp2 <<<(n + 127) / 128, 256, 0, stream>>>(hid16, W2_16p, b2, out, n);
}